// Round 9
// baseline (27.802 us; speedup 1.0000x reference)
//
#include <hip/hip_runtime.h>
#include <hip/hip_bf16.h>

using f32x4  = __attribute__((ext_vector_type(4))) float;
using bf16x8 = __attribute__((ext_vector_type(8))) short;

constexpr int   G_NUM = 256;
constexpr int   NAUG  = 256;
constexpr int   NORIG = 512;
constexpr int   DIM   = 128;
constexpr float INV_T = 10.0f;
constexpr int   NBLK  = 256;

// f32 stage: teacher rows DMA'd in pairs (1024B) with 16B pad per pair.
// Quarter tile = 64 rows = 32 pairs per slot; two slots double-buffered.
constexpr int PAIR_PITCH = 1040;                  // 1024 + 16
constexpr int SLOT_BYTES = 32 * PAIR_PITCH;       // 33280
constexpr int STAGE_BYTES = 2 * SLOT_BYTES;       // 66560

// Fixed-point tail encoding (exact, order-independent):
//   contrib = 2^55 (count) + (fixed + 2^45) where fixed = llrint(partial*2^30)
//   count field: 256*2^55 = 2^63 fits; sum field: <= 2^49 + 2^53 < 2^55 ✓
constexpr double FP_SCALE = 1073741824.0;          // 2^30
constexpr long long FP_BIAS = 1LL << 45;

// round-to-nearest-even f32 -> bf16 bits
__device__ __forceinline__ short f32_to_bf16_bits(float x) {
    unsigned u = __float_as_uint(x);
    u += 0x7fffu + ((u >> 16) & 1u);
    return (short)(u >> 16);
}

// 256 blocks = 1 per graph, 1 block/CU. 512 threads = 8 waves.
// R8 body (proven 22.62us): teacher gathered via global_load_lds in four
// 64-row quarters, double-buffered f32 stage, counted s_waitcnt vmcnt(4) +
// raw s_barrier so convert+MFMA of quarter k overlap DMA of k+1/k+2.
// Tail: single u64 atomicAdd of (count|fixed-point partial); the 256th
// arriver holds the exact total in-register (atomic return value) -> writes
// out. Integer adds commute -> bitwise deterministic; no fence, no re-read.
__global__ __launch_bounds__(512, 2) void nlcl_main(
    const float* __restrict__ student,
    const float* __restrict__ teacher,
    const int*   __restrict__ kept,
    unsigned long long* __restrict__ acc,
    float*       __restrict__ out)
{
    __shared__ __align__(16) char  stage[STAGE_BYTES];   // 2 slots, f32 quarters
    __shared__ __align__(16) short tile[NAUG * DIM];     // bf16 tile, swizzled, 64KB
    __shared__ float red[8];

    const int g    = blockIdx.x;
    const int tid  = threadIdx.x;
    const int lane = tid & 63;
    const int wave = tid >> 6;        // 0..7

    const float* s_base = student + (size_t)g * NAUG * DIM;
    const float* t_base = teacher + (size_t)g * NORIG * DIM;
    const int*   k_base = kept + g * NAUG;

    const int ccol  = lane & 15;      // frag row select / score col in tile
    const int cquad = lane >> 4;      // 0..3

    // ---- issue idx loads: quarter k, instr i covers pair k*32+wave*4+i ----
    int srcv[16];
    #pragma unroll
    for (int t = 0; t < 16; ++t) {
        const int pair = (t >> 2) * 32 + wave * 4 + (t & 3);
        srcv[t] = k_base[pair * 2 + (lane >> 5)];
    }

    // ---- issue student loads ----
    float4 sv[16];
    #pragma unroll
    for (int rt = 0; rt < 2; ++rt) {
        const float* rp = s_base + (wave * 32 + rt * 16 + ccol) * DIM;
        #pragma unroll
        for (int kc = 0; kc < 4; ++kc) {
            sv[rt * 8 + kc * 2]     = *reinterpret_cast<const float4*>(rp + kc * 32 + cquad * 8);
            sv[rt * 8 + kc * 2 + 1] = *reinterpret_cast<const float4*>(rp + kc * 32 + cquad * 8 + 4);
        }
    }

    // one DMA instr = 64 lanes x 16B = one row pair (lane>>5 = row in pair)
    auto dma_quarter = [&](int k) {
        #pragma unroll
        for (int i = 0; i < 4; ++i) {
            const float* src = t_base + (size_t)srcv[k * 4 + i] * DIM + (lane & 31) * 4;
            char* dst = stage + (k & 1) * SLOT_BYTES + (wave * 4 + i) * PAIR_PITCH;
            __builtin_amdgcn_global_load_lds(
                (const __attribute__((address_space(1))) void*)src,
                (__attribute__((address_space(3))) void*)dst, 16, 0, 0);
        }
    };

    // stage f32 quarter -> normalized bf16 tile rows 64k..64k+63
    auto convert_quarter = [&](int k) {
        const int row_l = tid >> 3;          // 0..63
        const int sub   = tid & 7;           // 16-float chunk
        const int j     = k * 64 + row_l;    // tile row
        const char* sp = stage + (k & 1) * SLOT_BYTES
                       + (row_l >> 1) * PAIR_PITCH + (row_l & 1) * 512 + sub * 64;
        float vals[16]; float ss = 0.f;
        #pragma unroll
        for (int it = 0; it < 4; ++it) {
            const float4 v = *reinterpret_cast<const float4*>(sp + it * 16);
            vals[it * 4] = v.x; vals[it * 4 + 1] = v.y;
            vals[it * 4 + 2] = v.z; vals[it * 4 + 3] = v.w;
            ss += v.x * v.x + v.y * v.y + v.z * v.z + v.w * v.w;
        }
        ss += __shfl_xor(ss, 1);
        ss += __shfl_xor(ss, 2);
        ss += __shfl_xor(ss, 4);
        const float scale = rsqrtf(fmaxf(ss, 1e-24f));
        char* tb = reinterpret_cast<char*>(tile);
        #pragma unroll
        for (int p = 0; p < 2; ++p) {
            bf16x8 o;
            #pragma unroll
            for (int e = 0; e < 8; ++e) o[e] = f32_to_bf16_bits(vals[p * 8 + e] * scale);
            const int byte = j * 256 + ((sub * 32 + p * 16) ^ ((j & 7) << 4));
            *reinterpret_cast<bf16x8*>(tb + byte) = o;
        }
    };

    // ---- issue quarters 0,1 DMA (fire-and-forget) ----
    dma_quarter(0);
    dma_quarter(1);

    // ---- student: normalize -> bf16 A-frags (overlaps DMA) ----
    bf16x8 afrag[2][4];
    #pragma unroll
    for (int rt = 0; rt < 2; ++rt) {
        float ss = 0.f;
        #pragma unroll
        for (int q = 0; q < 8; ++q) {
            const float4 v = sv[rt * 8 + q];
            ss += v.x * v.x + v.y * v.y + v.z * v.z + v.w * v.w;
        }
        ss += __shfl_xor(ss, 16);
        ss += __shfl_xor(ss, 32);
        const float scale = rsqrtf(fmaxf(ss, 1e-24f));
        #pragma unroll
        for (int kc = 0; kc < 4; ++kc) {
            const float4 a = sv[rt * 8 + kc * 2], b = sv[rt * 8 + kc * 2 + 1];
            afrag[rt][kc][0] = f32_to_bf16_bits(a.x * scale);
            afrag[rt][kc][1] = f32_to_bf16_bits(a.y * scale);
            afrag[rt][kc][2] = f32_to_bf16_bits(a.z * scale);
            afrag[rt][kc][3] = f32_to_bf16_bits(a.w * scale);
            afrag[rt][kc][4] = f32_to_bf16_bits(b.x * scale);
            afrag[rt][kc][5] = f32_to_bf16_bits(b.y * scale);
            afrag[rt][kc][6] = f32_to_bf16_bits(b.z * scale);
            afrag[rt][kc][7] = f32_to_bf16_bits(b.w * scale);
        }
    }

    float sumexp[2][4] = {{0.f,0.f,0.f,0.f},{0.f,0.f,0.f,0.f}};
    float diagsum = 0.f;
    const char* tlc = reinterpret_cast<const char*>(tile);

    // MFMA col-tiles 4k..4k+3 (tile rows 64k..64k+63)
    auto mfma_quarter = [&](int k) {
        #pragma unroll
        for (int ct = 4 * k; ct < 4 * k + 4; ++ct) {
            f32x4 acc0 = {0.f,0.f,0.f,0.f};
            f32x4 acc1 = {0.f,0.f,0.f,0.f};
            const int j = ct * 16 + ccol;
            #pragma unroll
            for (int kc = 0; kc < 4; ++kc) {
                const int byte = j * 256 + (((kc * 64) + (cquad * 16)) ^ ((j & 7) << 4));
                const bf16x8 b = *reinterpret_cast<const bf16x8*>(tlc + byte);
                acc0 = __builtin_amdgcn_mfma_f32_16x16x32_bf16(afrag[0][kc], b, acc0, 0, 0, 0);
                acc1 = __builtin_amdgcn_mfma_f32_16x16x32_bf16(afrag[1][kc], b, acc1, 0, 0, 0);
            }
            #pragma unroll
            for (int reg = 0; reg < 4; ++reg) {
                const int row0 = wave * 32 + cquad * 4 + reg;
                const int row1 = row0 + 16;
                const float l0 = acc0[reg] * INV_T;
                const float l1 = acc1[reg] * INV_T;
                sumexp[0][reg] += __expf(l0);
                sumexp[1][reg] += __expf(l1);
                if (j == row0) diagsum += l0;
                if (j == row1) diagsum += l1;
            }
        }
    };

    // ---- quarter pipeline ----
    asm volatile("s_waitcnt vmcnt(4)" ::: "memory");
    __builtin_amdgcn_s_barrier();
    convert_quarter(0);
    asm volatile("s_waitcnt lgkmcnt(0)" ::: "memory");
    __builtin_amdgcn_s_barrier();
    dma_quarter(2);                   // slot0 free
    mfma_quarter(0);                  // overlaps Q2 DMA

    asm volatile("s_waitcnt vmcnt(4)" ::: "memory");
    __builtin_amdgcn_s_barrier();
    convert_quarter(1);
    asm volatile("s_waitcnt lgkmcnt(0)" ::: "memory");
    __builtin_amdgcn_s_barrier();
    dma_quarter(3);                   // slot1 free
    mfma_quarter(1);                  // overlaps Q3 DMA

    asm volatile("s_waitcnt vmcnt(4)" ::: "memory");
    __builtin_amdgcn_s_barrier();
    convert_quarter(2);
    asm volatile("s_waitcnt lgkmcnt(0)" ::: "memory");
    __builtin_amdgcn_s_barrier();
    mfma_quarter(2);

    asm volatile("s_waitcnt vmcnt(0)" ::: "memory");
    __builtin_amdgcn_s_barrier();
    convert_quarter(3);
    asm volatile("s_waitcnt lgkmcnt(0)" ::: "memory");
    __builtin_amdgcn_s_barrier();
    mfma_quarter(3);

    // ---- per-block: sum_i log(sumexp_i) - sum_i diag_i ----
    float ce = 0.f;
    #pragma unroll
    for (int rt = 0; rt < 2; ++rt) {
        #pragma unroll
        for (int reg = 0; reg < 4; ++reg) {
            float s = sumexp[rt][reg];
            s += __shfl_xor(s, 1);
            s += __shfl_xor(s, 2);
            s += __shfl_xor(s, 4);
            s += __shfl_xor(s, 8);
            if (ccol == 0) ce += __logf(s);
        }
    }
    ce -= diagsum;
    ce += __shfl_xor(ce, 1);
    ce += __shfl_xor(ce, 2);
    ce += __shfl_xor(ce, 4);
    ce += __shfl_xor(ce, 8);
    ce += __shfl_xor(ce, 16);
    ce += __shfl_xor(ce, 32);

    if (lane == 0) red[wave] = ce;
    __syncthreads();

    // ---- exact integer single-atomic tail ----
    if (tid == 0) {
        float t = 0.f;
        #pragma unroll
        for (int w = 0; w < 8; ++w) t += red[w];
        // fixed-point encode: count (2^55) + bias (2^45) + value*2^30
        const long long fixed = llrintf(t * (float)FP_SCALE);
        const unsigned long long contrib =
            (1ULL << 55) + (unsigned long long)(fixed + FP_BIAS);
        const unsigned long long old = atomicAdd(acc, contrib);
        if ((unsigned)(old >> 55) == (unsigned)(NBLK - 1)) {
            // this is the 256th arrival: total is in-register, no re-read
            const unsigned long long tot55 =
                (old + contrib) & ((1ULL << 55) - 1);
            const double total =
                ((double)(long long)(tot55 - (unsigned long long)NBLK * FP_BIAS))
                * (1.0 / FP_SCALE);
            out[0] = (float)(total / ((double)G_NUM * (double)NAUG));
        }
    }
}

extern "C" void kernel_launch(void* const* d_in, const int* in_sizes, int n_in,
                              void* d_out, int out_size, void* d_ws, size_t ws_size,
                              hipStream_t stream) {
    (void)in_sizes; (void)n_in; (void)out_size; (void)ws_size;
    const float* student = (const float*)d_in[0];
    const float* teacher = (const float*)d_in[1];
    const int*   kept    = (const int*)d_in[2];

    unsigned long long* acc = (unsigned long long*)d_ws;   // 8B accumulator
    float* out = (float*)d_out;

    hipMemsetAsync(acc, 0, sizeof(unsigned long long), stream);
    nlcl_main<<<NBLK, 512, 0, stream>>>(student, teacher, kept, acc, out);
}

// Round 10
// 23.317 us; speedup vs baseline: 1.1923x; 1.1923x over previous
//
#include <hip/hip_runtime.h>
#include <hip/hip_bf16.h>

using f32x4  = __attribute__((ext_vector_type(4))) float;
using bf16x8 = __attribute__((ext_vector_type(8))) short;

constexpr int   G_NUM = 256;
constexpr int   NAUG  = 256;
constexpr int   NORIG = 512;
constexpr int   DIM   = 128;
constexpr float INV_T = 10.0f;
constexpr int   NBLK  = 256;

// f32 stage: teacher rows DMA'd in pairs (1024B) with 16B pad per pair.
// Quarter tile = 64 rows = 32 pairs per slot; two slots double-buffered.
constexpr int PAIR_PITCH = 1040;                  // 1024 + 16
constexpr int SLOT_BYTES = 32 * PAIR_PITCH;       // 33280
constexpr int STAGE_BYTES = 2 * SLOT_BYTES;       // 66560

// round-to-nearest-even f32 -> bf16 bits
__device__ __forceinline__ short f32_to_bf16_bits(float x) {
    unsigned u = __float_as_uint(x);
    u += 0x7fffu + ((u >> 16) & 1u);
    return (short)(u >> 16);
}

// 256 blocks = 1 per graph, 1 block/CU. 512 threads = 8 waves.
// Proven-best structure (R8, 22.62us):
//  - teacher rows gathered via global_load_lds (async DMA, no VGPR round
//    trip) in FOUR 64-row quarters into a double-buffered f32 stage
//  - counted s_waitcnt vmcnt(4) + raw s_barrier (never a full drain in the
//    steady state) so convert+MFMA of quarter k overlap DMA of k+1/k+2
//  - normalized bf16 tile is XOR-swizzled; MFMA 16x16x32 with in-register
//    student fragments; online sum-exp + diagonal capture; log at the end
//  - two-dispatch finish: tiny deterministic reduce kernel (all fused-tail
//    variants measured slower: R5 +4.3us, R9 +5.2us, R7 incorrect)
__global__ __launch_bounds__(512, 2) void nlcl_main(
    const float* __restrict__ student,
    const float* __restrict__ teacher,
    const int*   __restrict__ kept,
    float*       __restrict__ block_sums)
{
    __shared__ __align__(16) char  stage[STAGE_BYTES];   // 2 slots, f32 quarters
    __shared__ __align__(16) short tile[NAUG * DIM];     // bf16 tile, swizzled, 64KB
    __shared__ float red[8];

    const int g    = blockIdx.x;
    const int tid  = threadIdx.x;
    const int lane = tid & 63;
    const int wave = tid >> 6;        // 0..7

    const float* s_base = student + (size_t)g * NAUG * DIM;
    const float* t_base = teacher + (size_t)g * NORIG * DIM;
    const int*   k_base = kept + g * NAUG;

    const int ccol  = lane & 15;      // frag row select / score col in tile
    const int cquad = lane >> 4;      // 0..3

    // ---- issue idx loads: quarter k, instr i covers pair k*32+wave*4+i ----
    // this lane's row within the pair = lane>>5
    int srcv[16];
    #pragma unroll
    for (int t = 0; t < 16; ++t) {
        const int pair = (t >> 2) * 32 + wave * 4 + (t & 3);
        srcv[t] = k_base[pair * 2 + (lane >> 5)];
    }

    // ---- issue student loads ----
    float4 sv[16];
    #pragma unroll
    for (int rt = 0; rt < 2; ++rt) {
        const float* rp = s_base + (wave * 32 + rt * 16 + ccol) * DIM;
        #pragma unroll
        for (int kc = 0; kc < 4; ++kc) {
            sv[rt * 8 + kc * 2]     = *reinterpret_cast<const float4*>(rp + kc * 32 + cquad * 8);
            sv[rt * 8 + kc * 2 + 1] = *reinterpret_cast<const float4*>(rp + kc * 32 + cquad * 8 + 4);
        }
    }

    // one DMA instr = 64 lanes x 16B = one row pair (lane>>5 = row in pair)
    auto dma_quarter = [&](int k) {
        #pragma unroll
        for (int i = 0; i < 4; ++i) {
            const float* src = t_base + (size_t)srcv[k * 4 + i] * DIM + (lane & 31) * 4;
            char* dst = stage + (k & 1) * SLOT_BYTES + (wave * 4 + i) * PAIR_PITCH;
            __builtin_amdgcn_global_load_lds(
                (const __attribute__((address_space(1))) void*)src,
                (__attribute__((address_space(3))) void*)dst, 16, 0, 0);
        }
    };

    // stage f32 quarter -> normalized bf16 tile rows 64k..64k+63
    // 8 threads per row; each handles 16 floats.
    auto convert_quarter = [&](int k) {
        const int row_l = tid >> 3;          // 0..63
        const int sub   = tid & 7;           // 16-float chunk
        const int j     = k * 64 + row_l;    // tile row
        const char* sp = stage + (k & 1) * SLOT_BYTES
                       + (row_l >> 1) * PAIR_PITCH + (row_l & 1) * 512 + sub * 64;
        float vals[16]; float ss = 0.f;
        #pragma unroll
        for (int it = 0; it < 4; ++it) {
            const float4 v = *reinterpret_cast<const float4*>(sp + it * 16);
            vals[it * 4] = v.x; vals[it * 4 + 1] = v.y;
            vals[it * 4 + 2] = v.z; vals[it * 4 + 3] = v.w;
            ss += v.x * v.x + v.y * v.y + v.z * v.z + v.w * v.w;
        }
        ss += __shfl_xor(ss, 1);
        ss += __shfl_xor(ss, 2);
        ss += __shfl_xor(ss, 4);
        const float scale = rsqrtf(fmaxf(ss, 1e-24f));
        char* tb = reinterpret_cast<char*>(tile);
        #pragma unroll
        for (int p = 0; p < 2; ++p) {
            bf16x8 o;
            #pragma unroll
            for (int e = 0; e < 8; ++e) o[e] = f32_to_bf16_bits(vals[p * 8 + e] * scale);
            const int byte = j * 256 + ((sub * 32 + p * 16) ^ ((j & 7) << 4));
            *reinterpret_cast<bf16x8*>(tb + byte) = o;
        }
    };

    // ---- issue quarters 0,1 DMA (fire-and-forget) ----
    dma_quarter(0);
    dma_quarter(1);

    // ---- student: normalize -> bf16 A-frags (overlaps DMA) ----
    bf16x8 afrag[2][4];
    #pragma unroll
    for (int rt = 0; rt < 2; ++rt) {
        float ss = 0.f;
        #pragma unroll
        for (int q = 0; q < 8; ++q) {
            const float4 v = sv[rt * 8 + q];
            ss += v.x * v.x + v.y * v.y + v.z * v.z + v.w * v.w;
        }
        ss += __shfl_xor(ss, 16);
        ss += __shfl_xor(ss, 32);
        const float scale = rsqrtf(fmaxf(ss, 1e-24f));
        #pragma unroll
        for (int kc = 0; kc < 4; ++kc) {
            const float4 a = sv[rt * 8 + kc * 2], b = sv[rt * 8 + kc * 2 + 1];
            afrag[rt][kc][0] = f32_to_bf16_bits(a.x * scale);
            afrag[rt][kc][1] = f32_to_bf16_bits(a.y * scale);
            afrag[rt][kc][2] = f32_to_bf16_bits(a.z * scale);
            afrag[rt][kc][3] = f32_to_bf16_bits(a.w * scale);
            afrag[rt][kc][4] = f32_to_bf16_bits(b.x * scale);
            afrag[rt][kc][5] = f32_to_bf16_bits(b.y * scale);
            afrag[rt][kc][6] = f32_to_bf16_bits(b.z * scale);
            afrag[rt][kc][7] = f32_to_bf16_bits(b.w * scale);
        }
    }

    float sumexp[2][4] = {{0.f,0.f,0.f,0.f},{0.f,0.f,0.f,0.f}};
    float diagsum = 0.f;
    const char* tlc = reinterpret_cast<const char*>(tile);

    // MFMA col-tiles 4k..4k+3 (tile rows 64k..64k+63)
    auto mfma_quarter = [&](int k) {
        #pragma unroll
        for (int ct = 4 * k; ct < 4 * k + 4; ++ct) {
            f32x4 acc0 = {0.f,0.f,0.f,0.f};
            f32x4 acc1 = {0.f,0.f,0.f,0.f};
            const int j = ct * 16 + ccol;
            #pragma unroll
            for (int kc = 0; kc < 4; ++kc) {
                const int byte = j * 256 + (((kc * 64) + (cquad * 16)) ^ ((j & 7) << 4));
                const bf16x8 b = *reinterpret_cast<const bf16x8*>(tlc + byte);
                acc0 = __builtin_amdgcn_mfma_f32_16x16x32_bf16(afrag[0][kc], b, acc0, 0, 0, 0);
                acc1 = __builtin_amdgcn_mfma_f32_16x16x32_bf16(afrag[1][kc], b, acc1, 0, 0, 0);
            }
            #pragma unroll
            for (int reg = 0; reg < 4; ++reg) {
                const int row0 = wave * 32 + cquad * 4 + reg;
                const int row1 = row0 + 16;
                const float l0 = acc0[reg] * INV_T;
                const float l1 = acc1[reg] * INV_T;
                sumexp[0][reg] += __expf(l0);
                sumexp[1][reg] += __expf(l1);
                if (j == row0) diagsum += l0;
                if (j == row1) diagsum += l1;
            }
        }
    };

    // ---- quarter pipeline ----
    // k=0: wait Q0 (Q1's 4 newer ops keep Q0 out of the newest-4)
    asm volatile("s_waitcnt vmcnt(4)" ::: "memory");
    __builtin_amdgcn_s_barrier();
    convert_quarter(0);
    asm volatile("s_waitcnt lgkmcnt(0)" ::: "memory");
    __builtin_amdgcn_s_barrier();
    dma_quarter(2);                   // slot0 free (all waves past convert 0)
    mfma_quarter(0);                  // overlaps Q2 DMA

    // k=1
    asm volatile("s_waitcnt vmcnt(4)" ::: "memory");
    __builtin_amdgcn_s_barrier();
    convert_quarter(1);
    asm volatile("s_waitcnt lgkmcnt(0)" ::: "memory");
    __builtin_amdgcn_s_barrier();
    dma_quarter(3);                   // slot1 free
    mfma_quarter(1);                  // overlaps Q3 DMA

    // k=2
    asm volatile("s_waitcnt vmcnt(4)" ::: "memory");
    __builtin_amdgcn_s_barrier();
    convert_quarter(2);
    asm volatile("s_waitcnt lgkmcnt(0)" ::: "memory");
    __builtin_amdgcn_s_barrier();
    mfma_quarter(2);

    // k=3: last quarter -> full drain
    asm volatile("s_waitcnt vmcnt(0)" ::: "memory");
    __builtin_amdgcn_s_barrier();
    convert_quarter(3);
    asm volatile("s_waitcnt lgkmcnt(0)" ::: "memory");
    __builtin_amdgcn_s_barrier();
    mfma_quarter(3);

    // ---- per-block: sum_i log(sumexp_i) - sum_i diag_i ----
    float ce = 0.f;
    #pragma unroll
    for (int rt = 0; rt < 2; ++rt) {
        #pragma unroll
        for (int reg = 0; reg < 4; ++reg) {
            float s = sumexp[rt][reg];
            s += __shfl_xor(s, 1);
            s += __shfl_xor(s, 2);
            s += __shfl_xor(s, 4);
            s += __shfl_xor(s, 8);
            if (ccol == 0) ce += __logf(s);
        }
    }
    ce -= diagsum;
    ce += __shfl_xor(ce, 1);
    ce += __shfl_xor(ce, 2);
    ce += __shfl_xor(ce, 4);
    ce += __shfl_xor(ce, 8);
    ce += __shfl_xor(ce, 16);
    ce += __shfl_xor(ce, 32);

    if (lane == 0) red[wave] = ce;
    __syncthreads();
    if (tid == 0) {
        float t = 0.f;
        #pragma unroll
        for (int w = 0; w < 8; ++w) t += red[w];
        block_sums[g] = t;
    }
}

// Deterministic final reduction over 256 graph partials; out = sum / (G*NA)
__global__ void nlcl_reduce(const float* __restrict__ block_sums,
                            float* __restrict__ out)
{
    __shared__ float r[4];
    const int tid = threadIdx.x;   // 256 threads
    float v = block_sums[tid];
    v += __shfl_xor(v, 1);
    v += __shfl_xor(v, 2);
    v += __shfl_xor(v, 4);
    v += __shfl_xor(v, 8);
    v += __shfl_xor(v, 16);
    v += __shfl_xor(v, 32);
    if ((tid & 63) == 0) r[tid >> 6] = v;
    __syncthreads();
    if (tid == 0)
        out[0] = (r[0] + r[1] + r[2] + r[3]) * (1.0f / ((float)G_NUM * (float)NAUG));
}

extern "C" void kernel_launch(void* const* d_in, const int* in_sizes, int n_in,
                              void* d_out, int out_size, void* d_ws, size_t ws_size,
                              hipStream_t stream) {
    (void)in_sizes; (void)n_in; (void)out_size; (void)ws_size;
    const float* student = (const float*)d_in[0];
    const float* teacher = (const float*)d_in[1];
    const int*   kept    = (const int*)d_in[2];
    float* bs  = (float*)d_ws;
    float* out = (float*)d_out;

    nlcl_main<<<NBLK, 512, 0, stream>>>(student, teacher, kept, bs);
    nlcl_reduce<<<1, 256, 0, stream>>>(bs, out);
}